// Round 2
// baseline (542.714 us; speedup 1.0000x reference)
//
#include <hip/hip_runtime.h>
#include <stdint.h>
#include <math.h>

#define NTOK (1024 * 256)   // B*L
#define TPB  128            // tokens per block (fused kernel)
#define P_DIM 300
#define P_PAD 320           // padded K for MFMA (multiple of 32)
#define P_LDS 328           // LDS row stride in bf16 elems (656B rows, 16B-aligned)
#define E_DIM 256

typedef __attribute__((ext_vector_type(8))) short bf16x8_t;
typedef __attribute__((ext_vector_type(4))) float f32x4_t;

__device__ __forceinline__ unsigned short f2b(float f) {
    union { float f; unsigned int i; } v; v.f = f;
    unsigned int x = v.i;
    return (unsigned short)((x + 0x7FFFu + ((x >> 16) & 1u)) >> 16);  // RNE f32->bf16
}

// K0: convert+pad lin_w f32[256,300] -> bf16[256,320]. Tiny (81920 elems).
__global__ __launch_bounds__(256) void k0_convert(
        const float* __restrict__ lin_w, unsigned short* __restrict__ lin_w_pad) {
    int idx = blockIdx.x * 256 + threadIdx.x;
    int e = idx / P_PAD;
    int k = idx - e * P_PAD;
    lin_w_pad[idx] = (k < P_DIM) ? f2b(lin_w[(size_t)e * P_DIM + k]) : (unsigned short)0;
}

// Fused kernel: classify + regular-row copy + Poincare emb + MFMA GEMM,
// all block-local. 128 tokens/block, 256 threads (4 waves).
//  - classify: threads 0..127, LDS-atomic compaction of custom tokens
//  - regular rows: wave w copies tokens w*32..w*32+31 (1KB row per wave-iter)
//  - custom: ~26/block expected; chunks of 32 rows -> one 32x256 MFMA tile
//  - out stores are NON-TEMPORAL: out is write-once (268MB/iter); keep the
//    gather tables (regular_w 82MB, fixed/train 48MB) resident in L2/L3.
__global__ __launch_bounds__(256) void k_fused(
        const int* __restrict__ x, const int* __restrict__ v2c,
        const int* __restrict__ v2r,
        const float* __restrict__ fixed_w,
        const float* __restrict__ train_w,
        const float* __restrict__ regular_w,
        const unsigned short* __restrict__ lin_w_pad,
        const float* __restrict__ lin_b,
        float* __restrict__ out) {
    __shared__ __align__(16) unsigned short semb[32][P_LDS];
    __shared__ int stok[TPB];
    __shared__ int scm[TPB];
    __shared__ int rinfo[TPB];
    __shared__ int s_n;

    int tid  = threadIdx.x;
    int wid  = tid >> 6;
    int lane = tid & 63;
    int base = blockIdx.x * TPB;

    if (tid == 0) s_n = 0;
    __syncthreads();

    // ---- classify 128 tokens; block-local compaction (no global atomics) ----
    if (tid < TPB) {
        int t  = base + tid;
        int xv = x[t];
        int cm = v2c[xv];                 // mask == (cm != 0)
        int ri = -1;
        if (cm > 0) {
            int p = atomicAdd(&s_n, 1);   // LDS atomic, ~26 per block
            stok[p] = t;
            scm[p]  = cm;
        } else {
            ri = v2r[xv];
        }
        rinfo[tid] = ri;
    }
    __syncthreads();
    int n = s_n;

    // ---- regular rows: out = regular_w[ri] + lin_b ----
    f32x4_t lb4 = *(const f32x4_t*)(lin_b + lane * 4);
    #pragma unroll 4
    for (int it = 0; it < TPB / 4; it++) {
        int li = wid * (TPB / 4) + it;    // wave-uniform token slot
        int ri = rinfo[li];
        if (ri >= 0) {
            f32x4_t rf = *(const f32x4_t*)(regular_w + (size_t)ri * E_DIM + lane * 4);
            f32x4_t o = rf + lb4;
            __builtin_nontemporal_store(
                o, (f32x4_t*)(out + (size_t)(base + li) * E_DIM + lane * 4));
        }
    }

    if (n == 0) return;                   // block-uniform; no barriers follow

    // ---- epilogue constants (lin_b slice + padding regular row, == zeros) ----
    int col  = lane & 15;
    int kgrp = lane >> 4;
    int e0w  = wid * 64;
    int rbase = kgrp * 4;                 // C/D: col = lane&15, row = (lane>>4)*4 + reg
    float lbe[4], rr0[4];
    int rid0 = v2r[0];
    const float* rrow0 = regular_w + (size_t)rid0 * E_DIM;
    #pragma unroll
    for (int nt = 0; nt < 4; nt++) {
        lbe[nt] = lin_b[e0w + nt * 16 + col];
        rr0[nt] = rrow0[e0w + nt * 16 + col];
    }

    // ---- custom tokens in chunks of 32 rows ----
    for (int c0 = 0; c0 < n; c0 += 32) {
        int cn = n - c0; if (cn > 32) cn = 32;

        // Phase 1: Poincare embeddings -> bf16 LDS rows (wave-strided)
        for (int i = wid; i < cn; i += 4) {
            int cm = scm[c0 + i];
            const float* fw = fixed_w + (size_t)cm * P_DIM;
            const float* tw = train_w + (size_t)cm * P_DIM;
            float w[5], tr[5];
            float sw2 = 0.f, st2 = 0.f, swt = 0.f;
            #pragma unroll
            for (int s = 0; s < 5; s++) {
                int j = lane + 64 * s;
                float wv = 0.f, tv = 0.f;
                if (j < P_DIM) { wv = fw[j]; tv = tw[j]; }
                w[s] = wv; tr[s] = tv;
                sw2 = fmaf(wv, wv, sw2); st2 = fmaf(tv, tv, st2); swt = fmaf(wv, tv, swt);
            }
            #pragma unroll
            for (int m = 32; m >= 1; m >>= 1) {
                sw2 += __shfl_xor(sw2, m, 64);
                st2 += __shfl_xor(st2, m, 64);
                swt += __shfl_xor(swt, m, 64);
            }
            float norm = sqrtf(sw2);
            norm = fminf(norm, 0.9999999f);
            float scale = (norm > 0.f) ? (atanhf(norm) / norm) : 1.0f;
            float x2 = scale * scale * sw2;      // ||logmap0(w)||^2
            float y2 = st2;
            float xy = scale * swt;              // <logmap0(w), tr>
            float c1 = (1.f + 2.f * xy + y2) * scale;
            float c2 = (1.f - x2);
            float den = fmaxf(1.f + 2.f * xy + x2 * y2, 1e-15f);
            float inv = 1.f / den;
            #pragma unroll
            for (int s = 0; s < 5; s++) {
                int j = lane + 64 * s;           // covers 0..319
                float v = (j < P_DIM) ? (c1 * w[s] + c2 * tr[s]) * inv : 0.f;
                semb[i][j] = f2b(v);
            }
        }
        __syncthreads();

        // Phase 2: 32x256 MFMA tile (rows >= cn are garbage; masked at store,
        // and MFMA rows are independent so garbage/NaN cannot cross rows)
        f32x4_t acc[2][4];
        #pragma unroll
        for (int a = 0; a < 2; a++)
            #pragma unroll
            for (int b = 0; b < 4; b++) acc[a][b] = (f32x4_t)(0.f);

        #pragma unroll
        for (int kk = 0; kk < 10; kk++) {
            int k0 = kk * 32 + kgrp * 8;
            bf16x8_t afr[2], bfr[4];
            afr[0] = *(const bf16x8_t*)(&semb[col][k0]);
            afr[1] = *(const bf16x8_t*)(&semb[16 + col][k0]);
            #pragma unroll
            for (int nt = 0; nt < 4; nt++) {
                int e = e0w + nt * 16 + col;
                bfr[nt] = *(const bf16x8_t*)(lin_w_pad + (size_t)e * P_PAD + k0);
            }
            #pragma unroll
            for (int mt = 0; mt < 2; mt++)
                #pragma unroll
                for (int nt = 0; nt < 4; nt++)
                    acc[mt][nt] = __builtin_amdgcn_mfma_f32_16x16x32_bf16(
                        afr[mt], bfr[nt], acc[mt][nt], 0, 0, 0);
        }

        // epilogue: + lin_b + regular_w[v2r[0]] (zeros, kept for safety)
        #pragma unroll
        for (int mt = 0; mt < 2; mt++) {
            #pragma unroll
            for (int r = 0; r < 4; r++) {
                int row = mt * 16 + rbase + r;
                if (row < cn) {
                    int t = stok[c0 + row];
                    float* orow = out + (size_t)t * E_DIM;
                    #pragma unroll
                    for (int nt = 0; nt < 4; nt++) {
                        __builtin_nontemporal_store(
                            acc[mt][nt][r] + lbe[nt] + rr0[nt],
                            orow + e0w + nt * 16 + col);
                    }
                }
            }
        }
        __syncthreads();   // semb reuse by next chunk
    }
}

extern "C" void kernel_launch(void* const* d_in, const int* in_sizes, int n_in,
                              void* d_out, int out_size, void* d_ws, size_t ws_size,
                              hipStream_t stream) {
    const int* x   = (const int*)d_in[0];
    // d_in[1] = custom_indices (unused; vocab_to_custom[x]!=0 is equivalent to isin)
    const int* v2c = (const int*)d_in[2];
    const int* v2r = (const int*)d_in[3];
    const float* fixed_w   = (const float*)d_in[4];
    const float* train_w   = (const float*)d_in[5];
    const float* regular_w = (const float*)d_in[6];
    const float* lin_w     = (const float*)d_in[7];
    const float* lin_b     = (const float*)d_in[8];
    float* out = (float*)d_out;

    // ws layout: [lin_w_pad 160KB] — no counter/info/list needed anymore
    unsigned short* lin_w_pad = (unsigned short*)d_ws;

    k0_convert<<<(E_DIM * P_PAD) / 256, 256, 0, stream>>>(lin_w, lin_w_pad);
    k_fused<<<NTOK / TPB, 256, 0, stream>>>(x, v2c, v2r, fixed_w, train_w,
                                            regular_w, lin_w_pad, lin_b, out);
}

// Round 3
// 507.751 us; speedup vs baseline: 1.0689x; 1.0689x over previous
//
#include <hip/hip_runtime.h>
#include <stdint.h>
#include <math.h>

#define NTOK (1024 * 256)   // B*L
#define CPY_TOK 256         // tokens per copy block (4 waves x 64 tokens)
#define CUS_TOK 128         // tokens per custom block
#define P_DIM 300
#define P_PAD 320           // padded K for MFMA (multiple of 32)
#define P_LDS 328           // LDS row stride in bf16 elems (656B rows, 16B-aligned)
#define E_DIM 256

typedef __attribute__((ext_vector_type(8))) short bf16x8_t;
typedef __attribute__((ext_vector_type(4))) float f32x4_t;

__device__ __forceinline__ unsigned short f2b(float f) {
    union { float f; unsigned int i; } v; v.f = f;
    unsigned int x = v.i;
    return (unsigned short)((x + 0x7FFFu + ((x >> 16) & 1u)) >> 16);  // RNE f32->bf16
}

// kA: branchless regular-row copy for ALL tokens + fused lin_w bf16 convert.
//   out[t] = regular_w[v2r[x[t]]] + lin_b  (for custom tokens v2r[x]==0 -> pad
//   row of zeros + lin_b; kB overwrites those rows later in the same stream).
// Per wave: 64 tokens. Index gathers done once per-lane up front; per-token row
// base comes from __shfl with a LITERAL lane -> v_readlane -> SGPR base ->
// coalesced scalar-addressed loads, 8 rows in flight. No LDS, low VGPR.
__global__ __launch_bounds__(256) void kA_copy(
        const int* __restrict__ x, const int* __restrict__ v2r,
        const float* __restrict__ regular_w, const float* __restrict__ lin_b,
        const float* __restrict__ lin_w, unsigned short* __restrict__ lin_w_pad,
        float* __restrict__ out) {
    int tid  = threadIdx.x;
    int wid  = tid >> 6;
    int lane = tid & 63;

    // fused convert+pad lin_w f32[256,300] -> bf16[256,320] (first 320 blocks)
    if (blockIdx.x < (E_DIM * P_PAD) / 256) {
        int idx = blockIdx.x * 256 + tid;
        int e = idx / P_PAD;
        int k = idx - e * P_PAD;
        lin_w_pad[idx] = (k < P_DIM) ? f2b(lin_w[(size_t)e * P_DIM + k])
                                     : (unsigned short)0;
    }

    int base = blockIdx.x * CPY_TOK + wid * 64;
    int xv = x[base + lane];          // coalesced
    int rv = v2r[xv];                 // one gather per lane; ==0 for custom
    f32x4_t lb4 = *(const f32x4_t*)(lin_b + lane * 4);

    #pragma unroll 1
    for (int it0 = 0; it0 < 64; it0 += 8) {
        int ris[8];
        f32x4_t rows[8];
        #pragma unroll
        for (int u = 0; u < 8; u++) ris[u] = __shfl(rv, it0 + u, 64);
        #pragma unroll
        for (int u = 0; u < 8; u++)
            rows[u] = *(const f32x4_t*)(regular_w
                        + (size_t)ris[u] * E_DIM + lane * 4);
        #pragma unroll
        for (int u = 0; u < 8; u++) {
            f32x4_t o = rows[u] + lb4;
            __builtin_nontemporal_store(
                o, (f32x4_t*)(out + (size_t)(base + it0 + u) * E_DIM + lane * 4));
        }
    }
}

// kB: custom tokens only — block-local classify + Poincare emb + MFMA GEMM.
// 128 tokens/block, 256 threads (4 waves); ~26 custom tokens expected/block.
__global__ __launch_bounds__(256) void kB_custom(
        const int* __restrict__ x, const int* __restrict__ v2c,
        const int* __restrict__ v2r,
        const float* __restrict__ fixed_w,
        const float* __restrict__ train_w,
        const float* __restrict__ regular_w,
        const unsigned short* __restrict__ lin_w_pad,
        const float* __restrict__ lin_b,
        float* __restrict__ out) {
    __shared__ __align__(16) unsigned short semb[32][P_LDS];
    __shared__ int stok[CUS_TOK];
    __shared__ int scm[CUS_TOK];
    __shared__ int s_n;

    int tid  = threadIdx.x;
    int wid  = tid >> 6;
    int lane = tid & 63;
    int base = blockIdx.x * CUS_TOK;

    if (tid == 0) s_n = 0;
    __syncthreads();

    // ---- classify 128 tokens; block-local LDS compaction ----
    if (tid < CUS_TOK) {
        int t  = base + tid;
        int xv = x[t];
        int cm = v2c[xv];                 // mask == (cm != 0)
        if (cm > 0) {
            int p = atomicAdd(&s_n, 1);   // LDS atomic, ~26 per block
            stok[p] = t;
            scm[p]  = cm;
        }
    }
    __syncthreads();
    int n = s_n;
    if (n == 0) return;                   // block-uniform

    // ---- epilogue constants (lin_b slice + padding regular row, == zeros) ----
    int col   = lane & 15;
    int kgrp  = lane >> 4;
    int e0w   = wid * 64;
    int rbase = kgrp * 4;                 // C/D: col = lane&15, row = kgrp*4 + reg
    float lbe[4], rr0[4];
    int rid0 = v2r[0];
    const float* rrow0 = regular_w + (size_t)rid0 * E_DIM;
    #pragma unroll
    for (int nt = 0; nt < 4; nt++) {
        lbe[nt] = lin_b[e0w + nt * 16 + col];
        rr0[nt] = rrow0[e0w + nt * 16 + col];
    }

    // ---- custom tokens in chunks of 32 rows ----
    for (int c0 = 0; c0 < n; c0 += 32) {
        int cn = n - c0; if (cn > 32) cn = 32;

        // Phase 1: Poincare embeddings -> bf16 LDS rows (wave-strided)
        for (int i = wid; i < cn; i += 4) {
            int cm = scm[c0 + i];
            const float* fw = fixed_w + (size_t)cm * P_DIM;
            const float* tw = train_w + (size_t)cm * P_DIM;
            float w[5], tr[5];
            float sw2 = 0.f, st2 = 0.f, swt = 0.f;
            #pragma unroll
            for (int s = 0; s < 5; s++) {
                int j = lane + 64 * s;
                float wv = 0.f, tv = 0.f;
                if (j < P_DIM) { wv = fw[j]; tv = tw[j]; }
                w[s] = wv; tr[s] = tv;
                sw2 = fmaf(wv, wv, sw2); st2 = fmaf(tv, tv, st2); swt = fmaf(wv, tv, swt);
            }
            #pragma unroll
            for (int m = 32; m >= 1; m >>= 1) {
                sw2 += __shfl_xor(sw2, m, 64);
                st2 += __shfl_xor(st2, m, 64);
                swt += __shfl_xor(swt, m, 64);
            }
            float norm = sqrtf(sw2);
            norm = fminf(norm, 0.9999999f);
            float scale = (norm > 0.f) ? (atanhf(norm) / norm) : 1.0f;
            float x2 = scale * scale * sw2;      // ||logmap0(w)||^2
            float y2 = st2;
            float xy = scale * swt;              // <logmap0(w), tr>
            float c1 = (1.f + 2.f * xy + y2) * scale;
            float c2 = (1.f - x2);
            float den = fmaxf(1.f + 2.f * xy + x2 * y2, 1e-15f);
            float inv = 1.f / den;
            #pragma unroll
            for (int s = 0; s < 5; s++) {
                int j = lane + 64 * s;           // covers 0..319
                float v = (j < P_DIM) ? (c1 * w[s] + c2 * tr[s]) * inv : 0.f;
                semb[i][j] = f2b(v);
            }
        }
        __syncthreads();

        // Phase 2: 32x256 MFMA tile (rows >= cn are garbage; masked at store;
        // MFMA rows are independent so garbage cannot cross rows)
        f32x4_t acc[2][4];
        #pragma unroll
        for (int a = 0; a < 2; a++)
            #pragma unroll
            for (int b = 0; b < 4; b++) acc[a][b] = (f32x4_t)(0.f);

        #pragma unroll
        for (int kk = 0; kk < 10; kk++) {
            int k0 = kk * 32 + kgrp * 8;
            bf16x8_t afr[2], bfr[4];
            afr[0] = *(const bf16x8_t*)(&semb[col][k0]);
            afr[1] = *(const bf16x8_t*)(&semb[16 + col][k0]);
            #pragma unroll
            for (int nt = 0; nt < 4; nt++) {
                int e = e0w + nt * 16 + col;
                bfr[nt] = *(const bf16x8_t*)(lin_w_pad + (size_t)e * P_PAD + k0);
            }
            #pragma unroll
            for (int mt = 0; mt < 2; mt++)
                #pragma unroll
                for (int nt = 0; nt < 4; nt++)
                    acc[mt][nt] = __builtin_amdgcn_mfma_f32_16x16x32_bf16(
                        afr[mt], bfr[nt], acc[mt][nt], 0, 0, 0);
        }

        // epilogue: + lin_b + regular_w[v2r[0]] (zeros, kept for exactness)
        #pragma unroll
        for (int mt = 0; mt < 2; mt++) {
            #pragma unroll
            for (int r = 0; r < 4; r++) {
                int row = mt * 16 + rbase + r;
                if (row < cn) {
                    int t = stok[c0 + row];
                    float* orow = out + (size_t)t * E_DIM;
                    #pragma unroll
                    for (int nt = 0; nt < 4; nt++) {
                        __builtin_nontemporal_store(
                            acc[mt][nt][r] + lbe[nt] + rr0[nt],
                            orow + e0w + nt * 16 + col);
                    }
                }
            }
        }
        __syncthreads();   // semb reuse by next chunk
    }
}

extern "C" void kernel_launch(void* const* d_in, const int* in_sizes, int n_in,
                              void* d_out, int out_size, void* d_ws, size_t ws_size,
                              hipStream_t stream) {
    const int* x   = (const int*)d_in[0];
    // d_in[1] = custom_indices (unused; vocab_to_custom[x]!=0 is equivalent to isin)
    const int* v2c = (const int*)d_in[2];
    const int* v2r = (const int*)d_in[3];
    const float* fixed_w   = (const float*)d_in[4];
    const float* train_w   = (const float*)d_in[5];
    const float* regular_w = (const float*)d_in[6];
    const float* lin_w     = (const float*)d_in[7];
    const float* lin_b     = (const float*)d_in[8];
    float* out = (float*)d_out;

    // ws layout: [lin_w_pad 160KB] — no counter/info/list needed
    unsigned short* lin_w_pad = (unsigned short*)d_ws;

    kA_copy<<<NTOK / CPY_TOK, 256, 0, stream>>>(x, v2r, regular_w, lin_b,
                                                lin_w, lin_w_pad, out);
    kB_custom<<<NTOK / CUS_TOK, 256, 0, stream>>>(x, v2c, v2r, fixed_w, train_w,
                                                  regular_w, lin_w_pad, lin_b, out);
}